// Round 1
// baseline (313.533 us; speedup 1.0000x reference)
//
#include <hip/hip_runtime.h>
#include <hip/hip_bf16.h>

#define D_MODEL 768
#define N_HEADS 12
#define D_HEADK 64
#define BB 2
#define TT 2048
#define M_TOK (BB*TT)          // 4096
#define N_QKV (3*D_MODEL)      // 2304

using f32x4 = __attribute__((ext_vector_type(4))) float;
using s16x8 = __attribute__((ext_vector_type(8))) short;

__device__ __forceinline__ unsigned short f2bf(float f) {
    union { float f; unsigned u; } v; v.f = f;
    unsigned r = v.u + 0x7FFFu + ((v.u >> 16) & 1u);
    return (unsigned short)(r >> 16);
}

// ---------------- weight transpose: W [K][N] fp32 -> Wt [N][K] bf16 ----------
__global__ void wtrans_kernel(const float* __restrict__ W, unsigned short* __restrict__ Wt,
                              int K, int N) {
    __shared__ float tile[32][33];
    int bx = blockIdx.x * 32;  // n
    int by = blockIdx.y * 32;  // k
    int tx = threadIdx.x & 31;
    int ty = threadIdx.x >> 5;   // 0..7
    #pragma unroll
    for (int i = ty; i < 32; i += 8)
        tile[i][tx] = W[(size_t)(by + i) * N + bx + tx];
    __syncthreads();
    #pragma unroll
    for (int i = ty; i < 32; i += 8)
        Wt[(size_t)(bx + i) * K + by + tx] = f2bf(tile[tx][i]);
}

// ---------------- QKV GEMM: X[4096,768]fp32 x Wt[2304,768]bf16 -> Q,K,Vt ----
__launch_bounds__(256)
__global__ void qkv_kernel(const float* __restrict__ X, const unsigned short* __restrict__ Wt,
                           const float* __restrict__ bias,
                           unsigned short* __restrict__ Qw, unsigned short* __restrict__ Kw,
                           unsigned short* __restrict__ Vtw) {
    __shared__ unsigned short As[128][40];
    __shared__ unsigned short Bs[128][40];
    const int m0 = blockIdx.y * 128;
    const int n0 = blockIdx.x * 128;
    const int tid = threadIdx.x;
    const int l  = tid & 63;
    const int w  = tid >> 6;
    const int wr = w >> 1, wc = w & 1;
    const int lr = l & 15, lk = (l >> 4) * 8, li = (l >> 4) * 4;

    f32x4 acc[4][4] = {};
    for (int kt = 0; kt < D_MODEL; kt += 32) {
        // stage A: 128x32 fp32 -> bf16
        #pragma unroll
        for (int p = 0; p < 4; ++p) {
            int r = p * 32 + (tid >> 3);
            int c = (tid & 7) * 4;
            const float4 v = *(const float4*)&X[(size_t)(m0 + r) * D_MODEL + kt + c];
            ushort4 u;
            u.x = f2bf(v.x); u.y = f2bf(v.y); u.z = f2bf(v.z); u.w = f2bf(v.w);
            *(ushort4*)&As[r][c] = u;
        }
        // stage B: 128 rows (n) x 32 k, already bf16
        #pragma unroll
        for (int p = 0; p < 2; ++p) {
            int ch = tid * 2 + p;
            int r = ch >> 2;
            int c = (ch & 3) * 8;
            *(int4*)&Bs[r][c] = *(const int4*)&Wt[(size_t)(n0 + r) * D_MODEL + kt + c];
        }
        __syncthreads();
        s16x8 a[4], bf[4];
        #pragma unroll
        for (int mi = 0; mi < 4; ++mi)
            a[mi] = *(const s16x8*)&As[wr*64 + mi*16 + lr][lk];
        #pragma unroll
        for (int ni = 0; ni < 4; ++ni)
            bf[ni] = *(const s16x8*)&Bs[wc*64 + ni*16 + lr][lk];
        #pragma unroll
        for (int mi = 0; mi < 4; ++mi)
            #pragma unroll
            for (int ni = 0; ni < 4; ++ni)
                acc[mi][ni] = __builtin_amdgcn_mfma_f32_16x16x32_bf16(a[mi], bf[ni], acc[mi][ni], 0, 0, 0);
        __syncthreads();
    }
    // epilogue: scatter to Q (pre-scaled), K, V^T
    #pragma unroll
    for (int ni = 0; ni < 4; ++ni) {
        int ng = n0 + wc*64 + ni*16 + lr;
        int mat = ng / D_MODEL;       // uniform per block (128 | 768)
        int hd  = ng % D_MODEL;
        int h = hd >> 6, d = hd & 63;
        float bv = bias[ng];
        #pragma unroll
        for (int mi = 0; mi < 4; ++mi) {
            #pragma unroll
            for (int i = 0; i < 4; ++i) {
                int t  = m0 + wr*64 + mi*16 + li + i;
                int b  = t >> 11, tq = t & 2047;
                float val = acc[mi][ni][i] + bv;
                if (mat == 0) {
                    Qw[((size_t)(b*N_HEADS + h)*TT + tq)*64 + d] = f2bf(val * 0.125f);
                } else if (mat == 1) {
                    Kw[((size_t)(b*N_HEADS + h)*TT + tq)*64 + d] = f2bf(val);
                } else {
                    Vtw[((size_t)(b*N_HEADS + h)*64 + d)*TT + tq] = f2bf(val);
                }
            }
        }
    }
}

// ---------------- causal flash attention: 1 wave per 16 q-rows --------------
__launch_bounds__(64)
__global__ void attn_kernel(const unsigned short* __restrict__ Q,
                            const unsigned short* __restrict__ Kk,
                            const unsigned short* __restrict__ Vt,
                            unsigned short* __restrict__ Y) {
    __shared__ unsigned short P[16][40];
    const int bh = blockIdx.y;          // 0..23
    const int q0 = blockIdx.x * 16;
    const int b = bh / N_HEADS, h = bh % N_HEADS;
    const int l = threadIdx.x;
    const int lr = l & 15, lk = (l >> 4) * 8, li = (l >> 4) * 4;

    const unsigned short* Qp = Q  + (size_t)bh * TT * 64;
    const unsigned short* Kp = Kk + (size_t)bh * TT * 64;
    const unsigned short* Vp = Vt + (size_t)bh * 64 * TT;

    const s16x8 qa0 = *(const s16x8*)&Qp[(q0 + lr)*64 + lk];
    const s16x8 qa1 = *(const s16x8*)&Qp[(q0 + lr)*64 + lk + 32];

    float mi[4], si[4];
    f32x4 o[4] = {};
    #pragma unroll
    for (int i = 0; i < 4; ++i) { mi[i] = -1e30f; si[i] = 0.f; }

    for (int kt = 0; kt < q0 + 16; kt += 32) {
        f32x4 sc[2];
        #pragma unroll
        for (int kb = 0; kb < 2; ++kb) {
            int krow = kt + kb*16 + lr;
            s16x8 k0 = *(const s16x8*)&Kp[krow*64 + lk];
            s16x8 k1 = *(const s16x8*)&Kp[krow*64 + lk + 32];
            f32x4 z = {};
            z = __builtin_amdgcn_mfma_f32_16x16x32_bf16(qa0, k0, z, 0, 0, 0);
            z = __builtin_amdgcn_mfma_f32_16x16x32_bf16(qa1, k1, z, 0, 0, 0);
            sc[kb] = z;
        }
        if (kt + 31 > q0) {  // boundary tile: apply causal mask
            #pragma unroll
            for (int kb = 0; kb < 2; ++kb)
                #pragma unroll
                for (int i = 0; i < 4; ++i) {
                    int k = kt + kb*16 + lr;
                    int q = q0 + li + i;
                    if (k > q) sc[kb][i] = -1e30f;
                }
        }
        float e0[4], e1[4];
        #pragma unroll
        for (int i = 0; i < 4; ++i) {
            float pm = fmaxf(sc[0][i], sc[1][i]);
            #pragma unroll
            for (int off = 1; off < 16; off <<= 1)
                pm = fmaxf(pm, __shfl_xor(pm, off, 64));
            float mn = fmaxf(mi[i], pm);
            float sf = __expf(mi[i] - mn);
            e0[i] = __expf(sc[0][i] - mn);
            e1[i] = __expf(sc[1][i] - mn);
            float rs = e0[i] + e1[i];
            #pragma unroll
            for (int off = 1; off < 16; off <<= 1)
                rs += __shfl_xor(rs, off, 64);
            si[i] = si[i] * sf + rs;
            mi[i] = mn;
            #pragma unroll
            for (int c = 0; c < 4; ++c) o[c][i] *= sf;
        }
        __syncthreads();   // single wave: cheap; guards P WAR across iterations
        #pragma unroll
        for (int i = 0; i < 4; ++i) {
            P[li + i][lr]      = f2bf(e0[i]);
            P[li + i][16 + lr] = f2bf(e1[i]);
        }
        __syncthreads();
        const s16x8 pa = *(const s16x8*)&P[lr][lk];
        #pragma unroll
        for (int c = 0; c < 4; ++c) {
            s16x8 vb = *(const s16x8*)&Vp[(size_t)(c*16 + lr)*TT + kt + lk];
            o[c] = __builtin_amdgcn_mfma_f32_16x16x32_bf16(pa, vb, o[c], 0, 0, 0);
        }
    }
    #pragma unroll
    for (int i = 0; i < 4; ++i) {
        float inv = 1.f / si[i];
        int t = b*TT + q0 + li + i;
        #pragma unroll
        for (int c = 0; c < 4; ++c)
            Y[(size_t)t*D_MODEL + h*64 + c*16 + lr] = f2bf(o[c][i] * inv);
    }
}

// ---------------- proj GEMM: Y[4096,768]bf16 x Wt[768,768]bf16 + b -> fp32 --
__launch_bounds__(256)
__global__ void proj_kernel(const unsigned short* __restrict__ Y, const unsigned short* __restrict__ Wt,
                            const float* __restrict__ bias, float* __restrict__ Out) {
    __shared__ unsigned short As[128][40];
    __shared__ unsigned short Bs[128][40];
    const int m0 = blockIdx.y * 128;
    const int n0 = blockIdx.x * 128;
    const int tid = threadIdx.x;
    const int l  = tid & 63;
    const int w  = tid >> 6;
    const int wr = w >> 1, wc = w & 1;
    const int lr = l & 15, lk = (l >> 4) * 8, li = (l >> 4) * 4;

    f32x4 acc[4][4] = {};
    for (int kt = 0; kt < D_MODEL; kt += 32) {
        #pragma unroll
        for (int p = 0; p < 2; ++p) {
            int ch = tid * 2 + p;
            int r = ch >> 2;
            int c = (ch & 3) * 8;
            *(int4*)&As[r][c] = *(const int4*)&Y[(size_t)(m0 + r) * D_MODEL + kt + c];
            *(int4*)&Bs[r][c] = *(const int4*)&Wt[(size_t)(n0 + r) * D_MODEL + kt + c];
        }
        __syncthreads();
        s16x8 a[4], bf[4];
        #pragma unroll
        for (int mi = 0; mi < 4; ++mi)
            a[mi] = *(const s16x8*)&As[wr*64 + mi*16 + lr][lk];
        #pragma unroll
        for (int ni = 0; ni < 4; ++ni)
            bf[ni] = *(const s16x8*)&Bs[wc*64 + ni*16 + lr][lk];
        #pragma unroll
        for (int mi = 0; mi < 4; ++mi)
            #pragma unroll
            for (int ni = 0; ni < 4; ++ni)
                acc[mi][ni] = __builtin_amdgcn_mfma_f32_16x16x32_bf16(a[mi], bf[ni], acc[mi][ni], 0, 0, 0);
        __syncthreads();
    }
    #pragma unroll
    for (int ni = 0; ni < 4; ++ni) {
        int ng = n0 + wc*64 + ni*16 + lr;
        float bv = bias[ng];
        #pragma unroll
        for (int mj = 0; mj < 4; ++mj)
            #pragma unroll
            for (int i = 0; i < 4; ++i) {
                int t = m0 + wr*64 + mj*16 + li + i;
                Out[(size_t)t*D_MODEL + ng] = acc[mj][ni][i] + bv;
            }
    }
}

extern "C" void kernel_launch(void* const* d_in, const int* in_sizes, int n_in,
                              void* d_out, int out_size, void* d_ws, size_t ws_size,
                              hipStream_t stream) {
    const float* x      = (const float*)d_in[0];
    const float* w_attn = (const float*)d_in[1];
    const float* b_attn = (const float*)d_in[2];
    const float* w_proj = (const float*)d_in[3];
    const float* b_proj = (const float*)d_in[4];
    float* out = (float*)d_out;

    unsigned short* wt_attn = (unsigned short*)d_ws;                       // 2304*768
    unsigned short* wt_proj = wt_attn + (size_t)N_QKV * D_MODEL;           // 768*768
    unsigned short* Qw      = wt_proj + (size_t)D_MODEL * D_MODEL;         // 4096*768
    unsigned short* Kw      = Qw + (size_t)M_TOK * D_MODEL;
    unsigned short* Vtw     = Kw + (size_t)M_TOK * D_MODEL;
    unsigned short* Yw      = Vtw + (size_t)M_TOK * D_MODEL;

    hipLaunchKernelGGL(wtrans_kernel, dim3(N_QKV/32, D_MODEL/32), dim3(256), 0, stream,
                       w_attn, wt_attn, D_MODEL, N_QKV);
    hipLaunchKernelGGL(wtrans_kernel, dim3(D_MODEL/32, D_MODEL/32), dim3(256), 0, stream,
                       w_proj, wt_proj, D_MODEL, D_MODEL);
    hipLaunchKernelGGL(qkv_kernel, dim3(N_QKV/128, M_TOK/128), dim3(256), 0, stream,
                       x, wt_attn, b_attn, Qw, Kw, Vtw);
    hipLaunchKernelGGL(attn_kernel, dim3(TT/16, BB*N_HEADS), dim3(64), 0, stream,
                       Qw, Kw, Vtw, Yw);
    hipLaunchKernelGGL(proj_kernel, dim3(D_MODEL/128, M_TOK/128), dim3(256), 0, stream,
                       Yw, wt_proj, b_proj, out);
}